// Round 4
// baseline (143.129 us; speedup 1.0000x reference)
//
#include <hip/hip_runtime.h>

// ContrasPQ forward = per-(b,p) nearest-code lookup.
// s_k = sum_d c_kd * (-2 v_d) + ||c_k||^2  (drops ||v||^2, constant in k).
// R4: codebook stays in SGPRs (scalar loads through sK$ -- no LDS return-bus
// tax, which bound R1/R2 at ~65us). Scores use v_pk_fma_f32 with the code
// pair as the single legal SGPR operand (zero v_mov copies). Chunked
// software-pipelined s_loads hide SMEM latency (R3's stall). Argmin via
// min3 tree + strict-< chunk compare; index recovered by bit-exact
// winning-chunk recompute (all-VGPR pk_fma variant: same instruction, same
// math, divergent-safe).

typedef float f32x2 __attribute__((ext_vector_type(2)));
typedef float f32x4 __attribute__((ext_vector_type(4)));

#define TPB 128   // threads per block
#define KBQ 4     // queries per thread
#define CHUNK 4   // codes per chunk (SGPR budget: 2 x 32 = 64 for dbuf)

namespace {
constexpr int kB   = 8192;
constexpr int kEMB = 768;
constexpr int kP   = 96;
constexpr int kK   = 256;
constexpr int kD   = 8;
constexpr int kNCH = kK / CHUNK;  // 64 chunks
}

// pk_fma with wave-uniform (SGPR) code operand -- main loop only.
__device__ __forceinline__ f32x2 pk_fma_sv(f32x2 cs, f32x2 b, f32x2 acc) {
    f32x2 d;
    asm("v_pk_fma_f32 %0, %1, %2, %3" : "=v"(d) : "s"(cs), "v"(b), "v"(acc));
    return d;
}
// all-VGPR pk_fma -- epilogue (divergent operands). Same instruction =>
// bit-identical arithmetic vs pk_fma_sv.
__device__ __forceinline__ f32x2 pk_fma_vv(f32x2 a, f32x2 b, f32x2 acc) {
    f32x2 d;
    asm("v_pk_fma_f32 %0, %1, %2, %3" : "=v"(d) : "v"(a), "v"(b), "v"(acc));
    return d;
}

// ||c||^2: fixed serial fma chain -- identical expression at both call sites.
__device__ __forceinline__ float c2_of(f32x4 lo, f32x4 hi) {
    float t = lo.x * lo.x;
    t = fmaf(lo.y, lo.y, t);
    t = fmaf(lo.z, lo.z, t);
    t = fmaf(lo.w, lo.w, t);
    t = fmaf(hi.x, hi.x, t);
    t = fmaf(hi.y, hi.y, t);
    t = fmaf(hi.z, hi.z, t);
    t = fmaf(hi.w, hi.w, t);
    return t;
}

// score = c . vs + c2  (vs = -2*v), fixed pk chain + one horizontal add.
__device__ __forceinline__ float score_s(f32x4 lo, f32x4 hi,
                                         const f32x2 vs[4], f32x2 c2z) {
    f32x2 a = pk_fma_sv(lo.xy, vs[0], c2z);
    a = pk_fma_sv(lo.zw, vs[1], a);
    a = pk_fma_sv(hi.xy, vs[2], a);
    a = pk_fma_sv(hi.zw, vs[3], a);
    return a.x + a.y;
}
__device__ __forceinline__ float score_v(f32x4 lo, f32x4 hi,
                                         const f32x2 vs[4], f32x2 c2z) {
    f32x2 a = pk_fma_vv(lo.xy, vs[0], c2z);
    a = pk_fma_vv(lo.zw, vs[1], a);
    a = pk_fma_vv(hi.xy, vs[2], a);
    a = pk_fma_vv(hi.zw, vs[3], a);
    return a.x + a.y;
}

__device__ __forceinline__ void load_chunk(const float* __restrict__ cbp,
                                           int ch, f32x4 lo[CHUNK],
                                           f32x4 hi[CHUNK]) {
#pragma unroll
    for (int c = 0; c < CHUNK; ++c) {
        const f32x4* pc = reinterpret_cast<const f32x4*>(
            cbp + (ch * CHUNK + c) * kD);
        lo[c] = pc[0];
        hi[c] = pc[1];
    }
}

__global__ __launch_bounds__(TPB, 3)
void pq_argmin_kernel(const float* __restrict__ vecs,
                      const float* __restrict__ codebook,
                      float* __restrict__ out)
{
    const int p = blockIdx.y;
    const int t = threadIdx.x;

    // wave-uniform base for this p's 8 KB codebook slice (sK$-resident)
    const float* __restrict__ cbp = codebook + (size_t)p * kK * kD;

    // ---- load KBQ query subvectors, scale by -2 (exact pow2) ----
    const int b0 = blockIdx.x * (TPB * KBQ) + t;
    f32x2 vs[KBQ][4];
#pragma unroll
    for (int q = 0; q < KBQ; ++q) {
        const f32x4* vp = reinterpret_cast<const f32x4*>(
            vecs + (size_t)(b0 + q * TPB) * kEMB + p * kD);
        f32x4 x = vp[0];
        f32x4 y = vp[1];
        vs[q][0] = f32x2{-2.0f * x.x, -2.0f * x.y};
        vs[q][1] = f32x2{-2.0f * x.z, -2.0f * x.w};
        vs[q][2] = f32x2{-2.0f * y.x, -2.0f * y.y};
        vs[q][3] = f32x2{-2.0f * y.z, -2.0f * y.w};
    }

    float best[KBQ];
    int   bch[KBQ];
#pragma unroll
    for (int q = 0; q < KBQ; ++q) {
        best[q] = __builtin_inff();
        bch[q] = 0;
    }

    // ---- main loop: 64 chunks x 4 codes, software-pipelined s_loads ----
    f32x4 lo[CHUNK], hi[CHUNK];
    load_chunk(cbp, 0, lo, hi);

    for (int ch = 0; ch < kNCH; ++ch) {
        f32x4 nlo[CHUNK], nhi[CHUNK];
        load_chunk(cbp, (ch + 1) & (kNCH - 1), nlo, nhi);  // prefetch

        float c2[CHUNK];
        f32x2 c2z[CHUNK];
#pragma unroll
        for (int c = 0; c < CHUNK; ++c) {
            c2[c] = c2_of(lo[c], hi[c]);
            c2z[c] = f32x2{c2[c], 0.0f};
        }

#pragma unroll
        for (int q = 0; q < KBQ; ++q) {
            float s0 = score_s(lo[0], hi[0], vs[q], c2z[0]);
            float s1 = score_s(lo[1], hi[1], vs[q], c2z[1]);
            float s2 = score_s(lo[2], hi[2], vs[q], c2z[2]);
            float s3 = score_s(lo[3], hi[3], vs[q], c2z[3]);
            float m = fminf(fminf(fminf(s0, s1), s2), s3);  // min3 + min
            if (m < best[q]) {   // strict <: earlier chunk wins ties
                best[q] = m;
                bch[q] = ch;
            }
        }

#pragma unroll
        for (int c = 0; c < CHUNK; ++c) { lo[c] = nlo[c]; hi[c] = nhi[c]; }
    }

    // ---- epilogue: recompute winning chunk (bit-exact, divergent-safe),
    //      first-index match, emit codebook row ----
#pragma unroll
    for (int q = 0; q < KBQ; ++q) {
        const int base = bch[q] * CHUNK;
        float s[CHUNK];
#pragma unroll
        for (int c = 0; c < CHUNK; ++c) {
            const f32x4* pc = reinterpret_cast<const f32x4*>(
                cbp + (base + c) * kD);
            f32x4 clo = pc[0];
            f32x4 chi = pc[1];
            float cc2 = c2_of(clo, chi);
            s[c] = score_v(clo, chi, vs[q], f32x2{cc2, 0.0f});
        }
        int idx = base;
        bool fnd = (s[0] == best[q]);
#pragma unroll
        for (int c = 1; c < CHUNK; ++c) {
            bool e = (s[c] == best[q]) && !fnd;
            idx = e ? base + c : idx;
            fnd = fnd || (s[c] == best[q]);
        }
        const f32x4* row = reinterpret_cast<const f32x4*>(cbp + idx * kD);
        f32x4 r0 = row[0];
        f32x4 r1 = row[1];
        f32x4* op = reinterpret_cast<f32x4*>(
            out + (size_t)(b0 + q * TPB) * kEMB + p * kD);
        op[0] = r0;
        op[1] = r1;
    }
}

extern "C" void kernel_launch(void* const* d_in, const int* in_sizes, int n_in,
                              void* d_out, int out_size, void* d_ws, size_t ws_size,
                              hipStream_t stream)
{
    const float* vecs     = (const float*)d_in[0];
    const float* codebook = (const float*)d_in[1];
    float* out            = (float*)d_out;

    dim3 grid(kB / (TPB * KBQ), kP, 1);  // (16, 96) = 1536 blocks, 12 waves/CU
    dim3 block(TPB, 1, 1);
    hipLaunchKernelGGL(pq_argmin_kernel, grid, block, 0, stream,
                       vecs, codebook, out);
}

// Round 5
// 139.034 us; speedup vs baseline: 1.0295x; 1.0295x over previous
//
#include <hip/hip_runtime.h>

// ContrasPQ forward = per-(b,p) nearest-code lookup.
// s_k = c_k . (-2 v) + ||c_k||^2   (drops ||v||^2, constant in k).
// R5: LDS delivery amortized over KBQ=8 queries/thread; code-PAIR interleaved
// LDS layout so one v_pk_fma_f32 advances two codes' dots at once (no
// horizontal add). Argmin: 4-code chunks, min3 tree, strict-< chunk compare;
// index recovered by bit-exact winning-chunk recompute from global (L2-hot;
// avoids R2's divergent-LDS bank conflicts). pk_fma halves == IEEE scalar fma
// => epilogue scalar v_fma chain reproduces main-loop bits exactly.

typedef float f32x2 __attribute__((ext_vector_type(2)));
typedef float f32x4 __attribute__((ext_vector_type(4)));

#define TPB 128   // threads per block
#define KBQ 8     // queries per thread

namespace {
constexpr int kB   = 8192;
constexpr int kEMB = 768;
constexpr int kP   = 96;
constexpr int kK   = 256;
constexpr int kD   = 8;
constexpr int kNP  = kK / 2;   // 128 code-pairs
constexpr int kNCH = kK / 4;   // 64 chunks of 4 codes (2 pairs)
}

__device__ __forceinline__ f32x2 pk_fma(f32x2 a, f32x2 b, f32x2 c) {
    f32x2 d;
    asm("v_pk_fma_f32 %0, %1, %2, %3" : "=v"(d) : "v"(a), "v"(b), "v"(c));
    return d;
}

// ||c||^2: fixed serial fma chain -- identical at staging and epilogue.
__device__ __forceinline__ float c2_of(f32x4 lo, f32x4 hi) {
    float t = lo.x * lo.x;
    t = fmaf(lo.y, lo.y, t);
    t = fmaf(lo.z, lo.z, t);
    t = fmaf(lo.w, lo.w, t);
    t = fmaf(hi.x, hi.x, t);
    t = fmaf(hi.y, hi.y, t);
    t = fmaf(hi.z, hi.z, t);
    t = fmaf(hi.w, hi.w, t);
    return t;
}

__global__ __launch_bounds__(TPB, 2)
void pq_argmin_kernel(const float* __restrict__ vecs,
                      const float* __restrict__ codebook,
                      float* __restrict__ out)
{
    // [pair j][k] = {A_{2k}, B_{2k}, A_{2k+1}, B_{2k+1}}, A=code 2j, B=2j+1
    __shared__ alignas(16) f32x4 lds_pairs[kNP][4];  // 8 KB
    __shared__ alignas(16) f32x2 lds_c2[kNP];        // 1 KB  {c2_A, c2_B}

    const int p = blockIdx.y;
    const int t = threadIdx.x;
    const float* __restrict__ cbp = codebook + (size_t)p * kK * kD;
    const f32x4* cb4 = reinterpret_cast<const f32x4*>(cbp);

    // ---- stage pair t (codes 2t, 2t+1), interleaved by dim ----
    {
        f32x4 a0 = cb4[4 * t + 0];  // code 2t   dims 0..3
        f32x4 a1 = cb4[4 * t + 1];  // code 2t   dims 4..7
        f32x4 b0 = cb4[4 * t + 2];  // code 2t+1 dims 0..3
        f32x4 b1 = cb4[4 * t + 3];  // code 2t+1 dims 4..7
        lds_pairs[t][0] = f32x4{a0.x, b0.x, a0.y, b0.y};
        lds_pairs[t][1] = f32x4{a0.z, b0.z, a0.w, b0.w};
        lds_pairs[t][2] = f32x4{a1.x, b1.x, a1.y, b1.y};
        lds_pairs[t][3] = f32x4{a1.z, b1.z, a1.w, b1.w};
        lds_c2[t] = f32x2{c2_of(a0, a1), c2_of(b0, b1)};
    }

    // ---- load KBQ queries, scale by -2 (exact), duplicate per dim ----
    const int b0q = blockIdx.x * (TPB * KBQ) + t;
    f32x2 vd[KBQ][kD];  // vd[q][d] = {-2 v_d, -2 v_d}
#pragma unroll
    for (int q = 0; q < KBQ; ++q) {
        const f32x4* vp = reinterpret_cast<const f32x4*>(
            vecs + (size_t)(b0q + q * TPB) * kEMB + p * kD);
        f32x4 x = vp[0];
        f32x4 y = vp[1];
        float m0 = -2.0f * x.x, m1 = -2.0f * x.y, m2 = -2.0f * x.z,
              m3 = -2.0f * x.w, m4 = -2.0f * y.x, m5 = -2.0f * y.y,
              m6 = -2.0f * y.z, m7 = -2.0f * y.w;
        vd[q][0] = f32x2{m0, m0}; vd[q][1] = f32x2{m1, m1};
        vd[q][2] = f32x2{m2, m2}; vd[q][3] = f32x2{m3, m3};
        vd[q][4] = f32x2{m4, m4}; vd[q][5] = f32x2{m5, m5};
        vd[q][6] = f32x2{m6, m6}; vd[q][7] = f32x2{m7, m7};
    }
    __syncthreads();

    float best[KBQ];
    int   bch[KBQ];
#pragma unroll
    for (int q = 0; q < KBQ; ++q) {
        best[q] = __builtin_inff();
        bch[q] = 0;
    }

    // ---- main loop: 64 chunks x 4 codes (2 interleaved pairs) ----
#pragma unroll 2
    for (int ch = 0; ch < kNCH; ++ch) {
        f32x4 p0a = lds_pairs[2 * ch][0];
        f32x4 p0b = lds_pairs[2 * ch][1];
        f32x4 p0c = lds_pairs[2 * ch][2];
        f32x4 p0d = lds_pairs[2 * ch][3];
        f32x4 p1a = lds_pairs[2 * ch + 1][0];
        f32x4 p1b = lds_pairs[2 * ch + 1][1];
        f32x4 p1c = lds_pairs[2 * ch + 1][2];
        f32x4 p1d = lds_pairs[2 * ch + 1][3];
        f32x4 cz = *reinterpret_cast<const f32x4*>(&lds_c2[2 * ch]);

#pragma unroll
        for (int q = 0; q < KBQ; ++q) {
            f32x2 a0 = pk_fma(p0a.xy, vd[q][0], cz.xy);  // {s_4ch, s_4ch+1}
            a0 = pk_fma(p0a.zw, vd[q][1], a0);
            a0 = pk_fma(p0b.xy, vd[q][2], a0);
            a0 = pk_fma(p0b.zw, vd[q][3], a0);
            a0 = pk_fma(p0c.xy, vd[q][4], a0);
            a0 = pk_fma(p0c.zw, vd[q][5], a0);
            a0 = pk_fma(p0d.xy, vd[q][6], a0);
            a0 = pk_fma(p0d.zw, vd[q][7], a0);

            f32x2 a1 = pk_fma(p1a.xy, vd[q][0], cz.zw);  // {s_4ch+2, s_4ch+3}
            a1 = pk_fma(p1a.zw, vd[q][1], a1);
            a1 = pk_fma(p1b.xy, vd[q][2], a1);
            a1 = pk_fma(p1b.zw, vd[q][3], a1);
            a1 = pk_fma(p1c.xy, vd[q][4], a1);
            a1 = pk_fma(p1c.zw, vd[q][5], a1);
            a1 = pk_fma(p1d.xy, vd[q][6], a1);
            a1 = pk_fma(p1d.zw, vd[q][7], a1);

            // min3 + min (min of finites returns an operand bit-exactly)
            float m = fminf(fminf(fminf(a0.x, a0.y), a1.x), a1.y);
            if (m < best[q]) {   // strict <: earlier chunk wins ties
                best[q] = m;
                bch[q] = ch;
            }
        }
    }

    // ---- epilogue: bit-exact winning-chunk recompute from GLOBAL (L2-hot),
    //      first-index match, emit codebook row ----
#pragma unroll
    for (int q = 0; q < KBQ; ++q) {
        const int base = bch[q] * 4;
        float s[4];
#pragma unroll
        for (int c = 0; c < 4; ++c) {
            f32x4 lo = cb4[2 * (base + c)];
            f32x4 hi = cb4[2 * (base + c) + 1];
            float cc2 = c2_of(lo, hi);  // same chain as staging
            // scalar fma chain == pk_fma half, same dim order, same init
            float s_ = fmaf(lo.x, vd[q][0].x, cc2);
            s_ = fmaf(lo.y, vd[q][1].x, s_);
            s_ = fmaf(lo.z, vd[q][2].x, s_);
            s_ = fmaf(lo.w, vd[q][3].x, s_);
            s_ = fmaf(hi.x, vd[q][4].x, s_);
            s_ = fmaf(hi.y, vd[q][5].x, s_);
            s_ = fmaf(hi.z, vd[q][6].x, s_);
            s_ = fmaf(hi.w, vd[q][7].x, s_);
            s[c] = s_;
        }
        int idx = base;
        bool fnd = (s[0] == best[q]);
#pragma unroll
        for (int c = 1; c < 4; ++c) {
            bool e = (s[c] == best[q]) && !fnd;
            idx = e ? base + c : idx;
            fnd = fnd || (s[c] == best[q]);
        }
        f32x4 r0 = cb4[2 * idx];
        f32x4 r1 = cb4[2 * idx + 1];
        f32x4* op = reinterpret_cast<f32x4*>(
            out + (size_t)(b0q + q * TPB) * kEMB + p * kD);
        op[0] = r0;
        op[1] = r1;
    }
}

extern "C" void kernel_launch(void* const* d_in, const int* in_sizes, int n_in,
                              void* d_out, int out_size, void* d_ws, size_t ws_size,
                              hipStream_t stream)
{
    const float* vecs     = (const float*)d_in[0];
    const float* codebook = (const float*)d_in[1];
    float* out            = (float*)d_out;

    dim3 grid(kB / (TPB * KBQ), kP, 1);  // (8, 96) = 768 blocks = 3/CU even
    dim3 block(TPB, 1, 1);
    hipLaunchKernelGGL(pq_argmin_kernel, grid, block, 0, stream,
                       vecs, codebook, out);
}

// Round 6
// 136.453 us; speedup vs baseline: 1.0489x; 1.0189x over previous
//
#include <hip/hip_runtime.h>

// ContrasPQ forward = per-(b,p) nearest-code lookup.
// s_k = c_k . (-2 v) + ||c_k||^2   (drops ||v||^2, constant in k).
// R6: WAVE-SPLIT. Block = 4 waves x 512 queries (replicated); wave w scans
// only codes [64w,64w+64) -> codebook read from LDS ONCE PER BLOCK (576 b128)
// instead of once per wave (bound R1/R2 at 65us), while 6 blocks/CU keep
// 12-16 waves/CU resident (R5 died at 1.5 waves/SIMD). Query dims packed as
// pairs {-2v_d,-2v_{d+1}} broadcast via v_pk_fma_f32 op_sel (64 VGPRs, no dup
// movs). Cross-wave combine via LDS, ascending-wave strict-< (= global
// first-index tie-break); winning chunk recomputed bit-exactly (scalar fma
// chain == pk halves, same order, same memory).

typedef float f32x2 __attribute__((ext_vector_type(2)));
typedef float f32x4 __attribute__((ext_vector_type(4)));

#define TPB 256   // 4 waves
#define KBQ 8     // queries per lane (replicated across the block's waves)

namespace {
constexpr int kB   = 8192;
constexpr int kEMB = 768;
constexpr int kP   = 96;
constexpr int kK   = 256;
constexpr int kD   = 8;
constexpr int kNP  = kK / 2;        // 128 code-pairs
constexpr int kChW = 16;            // 4-code chunks per wave (64 codes)
}

// v_pk_fma_f32 with src1 LOW half broadcast to both lanes.
__device__ __forceinline__ f32x2 pk_bl(f32x2 cp, f32x2 qp, f32x2 acc) {
    f32x2 d;
    asm("v_pk_fma_f32 %0, %1, %2, %3 op_sel:[0,0,0] op_sel_hi:[1,0,1]"
        : "=v"(d) : "v"(cp), "v"(qp), "v"(acc));
    return d;
}
// v_pk_fma_f32 with src1 HIGH half broadcast to both lanes.
__device__ __forceinline__ f32x2 pk_bh(f32x2 cp, f32x2 qp, f32x2 acc) {
    f32x2 d;
    asm("v_pk_fma_f32 %0, %1, %2, %3 op_sel:[0,1,0] op_sel_hi:[1,1,1]"
        : "=v"(d) : "v"(cp), "v"(qp), "v"(acc));
    return d;
}

// ||c||^2: fixed serial fma chain -- identical at staging and epilogue.
__device__ __forceinline__ float c2_of(f32x4 lo, f32x4 hi) {
    float t = lo.x * lo.x;
    t = fmaf(lo.y, lo.y, t);
    t = fmaf(lo.z, lo.z, t);
    t = fmaf(lo.w, lo.w, t);
    t = fmaf(hi.x, hi.x, t);
    t = fmaf(hi.y, hi.y, t);
    t = fmaf(hi.z, hi.z, t);
    t = fmaf(hi.w, hi.w, t);
    return t;
}

__global__ __launch_bounds__(TPB, 3)
void pq_argmin_kernel(const float* __restrict__ vecs,
                      const float* __restrict__ codebook,
                      float* __restrict__ out)
{
    // [pair j][d2] = {A_{2d2}, B_{2d2}, A_{2d2+1}, B_{2d2+1}}  (A=2j, B=2j+1)
    __shared__ alignas(16) f32x4 lds_pairs[kNP][4];   // 8 KB
    __shared__ alignas(16) f32x2 lds_c2[kNP];         // 1 KB {c2_A, c2_B}
    __shared__ float lds_best[4][KBQ][64];            // 8 KB
    __shared__ int   lds_gch [4][KBQ][64];            // 8 KB

    const int p    = blockIdx.y;
    const int t    = threadIdx.x;
    const int lane = t & 63;
    const int w    = t >> 6;        // wave id 0..3 (wave-uniform)

    const float* __restrict__ cbp = codebook + (size_t)p * kK * kD;
    const f32x4* cb4 = reinterpret_cast<const f32x4*>(cbp);

    // ---- stage code-pair t (codes 2t,2t+1), dim-interleaved (waves 0-1) ----
    if (t < kNP) {
        f32x4 a0 = cb4[4 * t + 0];
        f32x4 a1 = cb4[4 * t + 1];
        f32x4 b0 = cb4[4 * t + 2];
        f32x4 b1 = cb4[4 * t + 3];
        lds_pairs[t][0] = f32x4{a0.x, b0.x, a0.y, b0.y};
        lds_pairs[t][1] = f32x4{a0.z, b0.z, a0.w, b0.w};
        lds_pairs[t][2] = f32x4{a1.x, b1.x, a1.y, b1.y};
        lds_pairs[t][3] = f32x4{a1.z, b1.z, a1.w, b1.w};
        lds_c2[t] = f32x2{c2_of(a0, a1), c2_of(b0, b1)};
    }

    // ---- load KBQ queries (same set in every wave), packed dim-pairs ----
    const int b0q = blockIdx.x * (64 * KBQ) + lane;
    f32x2 qp[KBQ][4];   // qp[q][j] = {-2 v_{2j}, -2 v_{2j+1}}
#pragma unroll
    for (int q = 0; q < KBQ; ++q) {
        const f32x4* vp = reinterpret_cast<const f32x4*>(
            vecs + (size_t)(b0q + q * 64) * kEMB + p * kD);
        f32x4 x = vp[0];
        f32x4 y = vp[1];
        qp[q][0] = f32x2{-2.0f * x.x, -2.0f * x.y};
        qp[q][1] = f32x2{-2.0f * x.z, -2.0f * x.w};
        qp[q][2] = f32x2{-2.0f * y.x, -2.0f * y.y};
        qp[q][3] = f32x2{-2.0f * y.z, -2.0f * y.w};
    }
    __syncthreads();

    float best[KBQ];
    int   bgch[KBQ];    // GLOBAL 4-code chunk index (0..63)
#pragma unroll
    for (int q = 0; q < KBQ; ++q) {
        best[q] = __builtin_inff();
        bgch[q] = w * kChW;
    }

    // ---- main loop: this wave's 16 chunks x 4 codes (2 interleaved pairs) --
#pragma unroll 2
    for (int ch = 0; ch < kChW; ++ch) {
        const int g  = w * kChW + ch;   // global chunk
        const int pb = 2 * g;           // first pair index
        f32x4 P0a = lds_pairs[pb][0];
        f32x4 P0b = lds_pairs[pb][1];
        f32x4 P0c = lds_pairs[pb][2];
        f32x4 P0d = lds_pairs[pb][3];
        f32x4 P1a = lds_pairs[pb + 1][0];
        f32x4 P1b = lds_pairs[pb + 1][1];
        f32x4 P1c = lds_pairs[pb + 1][2];
        f32x4 P1d = lds_pairs[pb + 1][3];
        f32x4 cz  = *reinterpret_cast<const f32x4*>(&lds_c2[pb]);

#pragma unroll
        for (int q = 0; q < KBQ; ++q) {
            f32x2 a0 = pk_bl(P0a.xy, qp[q][0], cz.xy);   // dim 0
            a0 = pk_bh(P0a.zw, qp[q][0], a0);            // dim 1
            a0 = pk_bl(P0b.xy, qp[q][1], a0);            // dim 2
            a0 = pk_bh(P0b.zw, qp[q][1], a0);            // dim 3
            a0 = pk_bl(P0c.xy, qp[q][2], a0);            // dim 4
            a0 = pk_bh(P0c.zw, qp[q][2], a0);            // dim 5
            a0 = pk_bl(P0d.xy, qp[q][3], a0);            // dim 6
            a0 = pk_bh(P0d.zw, qp[q][3], a0);            // dim 7

            f32x2 a1 = pk_bl(P1a.xy, qp[q][0], cz.zw);
            a1 = pk_bh(P1a.zw, qp[q][0], a1);
            a1 = pk_bl(P1b.xy, qp[q][1], a1);
            a1 = pk_bh(P1b.zw, qp[q][1], a1);
            a1 = pk_bl(P1c.xy, qp[q][2], a1);
            a1 = pk_bh(P1c.zw, qp[q][2], a1);
            a1 = pk_bl(P1d.xy, qp[q][3], a1);
            a1 = pk_bh(P1d.zw, qp[q][3], a1);

            float m = fminf(fminf(fminf(a0.x, a0.y), a1.x), a1.y);
            if (m < best[q]) {   // strict <: earlier (lower-index) chunk wins
                best[q] = m;
                bgch[q] = g;
            }
        }
    }

    // ---- publish per-wave partials, combine in ascending wave order ----
#pragma unroll
    for (int q = 0; q < KBQ; ++q) {
        lds_best[w][q][lane] = best[q];
        lds_gch [w][q][lane] = bgch[q];
    }
    __syncthreads();

    // wave w finalizes queries {2w, 2w+1}
#pragma unroll
    for (int qi = 0; qi < 2; ++qi) {
        const int q = 2 * w + qi;
        float bb = lds_best[0][q][lane];
        int   gc = lds_gch [0][q][lane];
#pragma unroll
        for (int wv = 1; wv < 4; ++wv) {
            float b2 = lds_best[wv][q][lane];
            int   g2 = lds_gch [wv][q][lane];
            bool c = (b2 < bb);          // strict <: lower wave wins ties
            bb = c ? b2 : bb;
            gc = c ? g2 : gc;
        }
        // bit-exact recompute of the 4 winning-chunk scores from global (L2)
        const int base = gc * 4;
        float s[4];
#pragma unroll
        for (int c = 0; c < 4; ++c) {
            f32x4 lo = cb4[2 * (base + c)];
            f32x4 hi = cb4[2 * (base + c) + 1];
            float cc2 = c2_of(lo, hi);
            float s_ = fmaf(lo.x, qp[q][0].x, cc2);
            s_ = fmaf(lo.y, qp[q][0].y, s_);
            s_ = fmaf(lo.z, qp[q][1].x, s_);
            s_ = fmaf(lo.w, qp[q][1].y, s_);
            s_ = fmaf(hi.x, qp[q][2].x, s_);
            s_ = fmaf(hi.y, qp[q][2].y, s_);
            s_ = fmaf(hi.z, qp[q][3].x, s_);
            s_ = fmaf(hi.w, qp[q][3].y, s_);
            s[c] = s_;
        }
        int idx = base;
        bool fnd = (s[0] == bb);
#pragma unroll
        for (int c = 1; c < 4; ++c) {
            bool e = (s[c] == bb) && !fnd;
            idx = e ? base + c : idx;
            fnd = fnd || (s[c] == bb);
        }
        f32x4 r0 = cb4[2 * idx];
        f32x4 r1 = cb4[2 * idx + 1];
        f32x4* op = reinterpret_cast<f32x4*>(
            out + (size_t)(b0q + q * 64) * kEMB + p * kD);
        op[0] = r0;
        op[1] = r1;
    }
}

extern "C" void kernel_launch(void* const* d_in, const int* in_sizes, int n_in,
                              void* d_out, int out_size, void* d_ws, size_t ws_size,
                              hipStream_t stream)
{
    const float* vecs     = (const float*)d_in[0];
    const float* codebook = (const float*)d_in[1];
    float* out            = (float*)d_out;

    dim3 grid(kB / (64 * KBQ), kP, 1);  // (16, 96) = 1536 blocks = 6/CU
    dim3 block(TPB, 1, 1);
    hipLaunchKernelGGL(pq_argmin_kernel, grid, block, 0, stream,
                       vecs, codebook, out);
}